// Round 15
// baseline (282.831 us; speedup 1.0000x reference)
//
#include <hip/hip_runtime.h>

// ---------------------------------------------------------------------------
// AttnBlock: LN(channel) -> QKV 1x1 conv -> full attention (L=4096, d=512)
//            -> proj -> SELU -> residual.   B=4, C=512, L=4096.  bf16 MFMA.
// Round 15: combine2 fused into gemm_pp — position operand reg-staged as
// (O0+O1)*inv(l0+l1) directly into the (verified) swizzled LDS layout.
// Saves 32MB traffic + one launch. Flash/QKV/LN frozen (r14).
// ---------------------------------------------------------------------------

typedef __attribute__((ext_vector_type(8))) __bf16 bf16x8;
typedef __attribute__((ext_vector_type(4))) __bf16 bf16x4;
typedef __attribute__((ext_vector_type(4))) float  f32x4;

__device__ __forceinline__ f32x4 mfma16(bf16x8 a, bf16x8 b, f32x4 c) {
  return __builtin_amdgcn_mfma_f32_16x16x32_bf16(a, b, c, 0, 0, 0);
}

// async global->LDS, 16B per lane; lds dest is wave-uniform base (HW adds lane*16)
__device__ __forceinline__ void gll16(const void* g, void* l) {
  __builtin_amdgcn_global_load_lds(
      (const __attribute__((address_space(1))) unsigned int*)g,
      (__attribute__((address_space(3))) unsigned int*)l, 16, 0, 0);
}

__device__ __forceinline__ float selu_f(float v) {
  return 1.0507009873554805f * (v > 0.f ? v : 1.6732632423543772f * (__expf(v) - 1.f));
}

// log2(e) / sqrt(512): folded into q at the QKV-GEMM epilogue
#define QSCALE ((float)(1.4426950408889634 / 22.627416997969522))

// ---------------------------------------------------------------------------
// Fused LN (single-pass) + weight cvt, one launch (r14-verified).
// ---------------------------------------------------------------------------
__global__ __launch_bounds__(256) void ln_cvt(
    const float* __restrict__ x, const float* __restrict__ lw,
    const float* __restrict__ lb, __bf16* __restrict__ h,
    const float* __restrict__ w0, const float* __restrict__ w1,
    const float* __restrict__ w2, const float* __restrict__ w3,
    __bf16* __restrict__ wdst) {
  __shared__ float xf[512][33];               // 67.6 KB
  __shared__ float red[32][8][4][2];          // 8 KB
  __shared__ float smu[32], srs[32];
  const int id = blockIdx.x, tid = threadIdx.x;

  if (id >= 512) {
    // ---- weight convert path ----
    int idx = (id - 512) * 256 + tid;          // 0..262143 (x4 floats)
    int which = idx >> 16;
    const float* s = which == 0 ? w0 : which == 1 ? w1 : which == 2 ? w2 : w3;
    f32x4 v = *(const f32x4*)(s + (size_t)(idx & 65535) * 4);
    bf16x4 o = {(__bf16)v.x, (__bf16)v.y, (__bf16)v.z, (__bf16)v.w};
    *(bf16x4*)(wdst + (size_t)idx * 4) = o;
    return;
  }

  // ---- LN path: 32 l-positions x 512 channels ----
  const int b = id >> 7, l0 = (id & 127) * 32;
  const int hi = tid >> 3, lq = tid & 7;       // hi 0..31, lq 0..7 (l quad)

  {
    const float* xp = x + (size_t)b * 2097152 + l0 + lq * 4;
    float s[4] = {0.f, 0.f, 0.f, 0.f}, qq[4] = {0.f, 0.f, 0.f, 0.f};
#pragma unroll
    for (int it = 0; it < 16; ++it) {
      int c = it * 32 + hi;
      f32x4 v = *(const f32x4*)(xp + (size_t)c * 4096);
#pragma unroll
      for (int k = 0; k < 4; ++k) {
        s[k] += v[k];
        qq[k] += v[k] * v[k];
        xf[c][lq * 4 + k] = v[k];
      }
    }
#pragma unroll
    for (int k = 0; k < 4; ++k) {
      red[hi][lq][k][0] = s[k];
      red[hi][lq][k][1] = qq[k];
    }
  }
  __syncthreads();
  if (tid < 32) {
    int l4 = tid >> 2, k = tid & 3;
    float S = 0.f, Q = 0.f;
#pragma unroll
    for (int hh = 0; hh < 32; ++hh) {
      S += red[hh][l4][k][0];
      Q += red[hh][l4][k][1];
    }
    float m = S * (1.f / 512.f);
    float var = Q * (1.f / 512.f) - m * m;
    smu[tid] = m;
    srs[tid] = rsqrtf(var + 1e-5f);
  }
  __syncthreads();

#pragma unroll
  for (int l = 0; l < 32; ++l) {
    float m = smu[l], r = srs[l];
#pragma unroll
    for (int st = 0; st < 2; ++st) {
      int c = st * 256 + tid;
      float v = (xf[c][l] - m) * r * lw[c] + lb[c];
      h[((size_t)b * 4096 + l0 + l) * 512 + c] = (__bf16)v;
    }
  }
}

// ---------------------------------------------------------------------------
// 128x128 bf16 GEMM, C[i][j] = sum_k A[i][k]*W[j][k], K=512, BK=128 (4 iters).
// Epilogues restage C through LDS for coalesced stores (r13-verified).
// ---------------------------------------------------------------------------
__global__ __launch_bounds__(256, 2) void gemm_qkv(
    const __bf16* __restrict__ A, const __bf16* __restrict__ W,
    const float* __restrict__ b0, const float* __restrict__ b1,
    const float* __restrict__ b2, __bf16* __restrict__ out,
    __bf16* __restrict__ vt) {
  __shared__ __align__(16) __bf16 smem[2 * 128 * 128];  // 64 KB
  __bf16* As = smem;
  __bf16* Bs = smem + 16384;
  const int tid = threadIdx.x;
  const int w = tid >> 6, lane = tid & 63, g = lane >> 4, li = lane & 15;
  // 1536 blocks: xcd = id&7 owns m-tiles [16*xcd, 16*xcd+16) x all 12 n-tiles
  const int id = blockIdx.x;
  const int jj = id >> 3;
  const int m0 = (16 * (id & 7) + jj / 12) * 128;
  const int n0 = (jj % 12) * 128;
  const int wm = w >> 1, wn = w & 1;
  const int srow = lane >> 4;                  // 0..3 (row within gll16 call)
  f32x4 acc[4][4] = {};
  for (int kt = 0; kt < 4; ++kt) {
    __syncthreads();
#pragma unroll
    for (int qq = 0; qq < 8; ++qq) {
      int r = w * 32 + qq * 4;                 // wave-uniform row block (4 rows)
      int gr = (lane & 15) ^ (4 * (qq & 1) + srow);  // pre-swizzled src granule
      gll16(A + (size_t)(m0 + r + srow) * 512 + kt * 128 + gr * 8, &As[r * 128]);
      gll16(W + (size_t)(n0 + r + srow) * 512 + kt * 128 + gr * 8, &Bs[r * 128]);
    }
    __syncthreads();
#pragma unroll
    for (int kk = 0; kk < 4; ++kk) {
      bf16x8 af[4], bf[4];
#pragma unroll
      for (int t = 0; t < 4; ++t) {
        int ra = wm * 64 + t * 16 + li;
        af[t] = *(const bf16x8*)&As[ra * 128 + ((kk * 32 + 8 * g) ^ ((ra & 7) * 8))];
        int rb = wn * 64 + t * 16 + li;
        bf[t] = *(const bf16x8*)&Bs[rb * 128 + ((kk * 32 + 8 * g) ^ ((rb & 7) * 8))];
      }
#pragma unroll
      for (int i = 0; i < 4; ++i)
#pragma unroll
        for (int j = 0; j < 4; ++j) acc[i][j] = mfma16(af[i], bf[j], acc[i][j]);
    }
  }
  const int which = n0 >> 9;  // 0=q,1=k,2=v (block never crosses a 512 boundary)
  __syncthreads();            // all MFMA reads of As/Bs complete before reuse
  if (which < 2) {
    const float* bb = which == 0 ? b0 : b1;
    const float sc = which == 0 ? QSCALE : 1.0f;
    // stage C row-major [128][128] in smem
#pragma unroll
    for (int i = 0; i < 4; ++i) {
#pragma unroll
      for (int j = 0; j < 4; ++j) {
        int rl = wm * 64 + i * 16 + 4 * g;
        int cl = wn * 64 + j * 16 + li;
        float bv = bb[(n0 & 511) + cl];
#pragma unroll
        for (int e = 0; e < 4; ++e)
          smem[(rl + e) * 128 + cl] = (__bf16)((acc[i][j][e] + bv) * sc);
      }
    }
    __syncthreads();
    __bf16* o = out + (size_t)which * 8388608;
#pragma unroll
    for (int rep = 0; rep < 8; ++rep) {
      int ii = rep * 256 + tid;            // 0..2047
      int row = ii >> 4, col8 = (ii & 15) * 8;
      *(bf16x8*)&o[(size_t)(m0 + row) * 512 + (n0 & 511) + col8] =
          *(const bf16x8*)&smem[row * 128 + col8];
    }
  } else {
    // stage C col-major [chan][pos], stride 136 (16B-aligned rows)
#pragma unroll
    for (int i = 0; i < 4; ++i) {
#pragma unroll
      for (int j = 0; j < 4; ++j) {
        int rl = wm * 64 + i * 16 + 4 * g;   // pos base (mult of 4)
        int cl = wn * 64 + j * 16 + li;      // chan
        float bv = b2[(n0 & 511) + cl];
        bf16x4 pk = {(__bf16)(acc[i][j][0] + bv), (__bf16)(acc[i][j][1] + bv),
                     (__bf16)(acc[i][j][2] + bv), (__bf16)(acc[i][j][3] + bv)};
        *(bf16x4*)&smem[cl * 136 + rl] = pk;
      }
    }
    __syncthreads();
    const int bb_ = m0 >> 12, l0_ = m0 & 4095;
#pragma unroll
    for (int rep = 0; rep < 8; ++rep) {
      int chan = rep * 16 + (tid >> 4);
      int l8 = (tid & 15) * 8;
      *(bf16x8*)&vt[((size_t)(bb_ * 512) + (n0 & 511) + chan) * 4096 + l0_ + l8] =
          *(const bf16x8*)&smem[chan * 136 + l8];
    }
  }
}

// PP variant (BK=128) with fused combine: position operand built on the fly
// as (O0+O1)*inv(l0+l1), reg-staged into the SAME swizzled LDS layout that
// gll16 staging produced (slot s of row R holds source granule s^(R&7)).
// Epilogue bias+SELU+residual, writes out[b][o][l] fp32 coalesced.
__global__ __launch_bounds__(256, 2) void gemm_pp(
    const __bf16* __restrict__ A, const __bf16* __restrict__ O0,
    const __bf16* __restrict__ O1, const float* __restrict__ stats,
    const float* __restrict__ bias, const float* __restrict__ xres,
    float* __restrict__ out) {
  __shared__ __align__(16) __bf16 As[128 * 128];
  __shared__ __align__(16) __bf16 Bs[128 * 128];
  __shared__ float invl[128];
  const int tid = threadIdx.x;
  const int w = tid >> 6, lane = tid & 63, g = lane >> 4, li = lane & 15;
  // 512 blocks: xcd = id&7 owns position-tiles [16*xcd,16*xcd+16) x 4 m-tiles
  const int id = blockIdx.x;
  const int jj = id >> 3;
  const int n0 = (16 * (id & 7) + (jj & 15)) * 128;  // position
  const int m0 = (jj >> 4) * 128;                    // output channel
  const int wm = w >> 1, wn = w & 1;
  const int srow = lane >> 4;
  if (tid < 128) {
    int p = n0 + tid;
    invl[tid] = 1.f / (stats[p] + stats[16384 + p]);
  }
  f32x4 acc[4][4] = {};
  for (int kt = 0; kt < 4; ++kt) {
    __syncthreads();   // (kt=0: invl visible; kt>0: As/Bs reads done)
#pragma unroll
    for (int qq = 0; qq < 8; ++qq) {
      int r = w * 32 + qq * 4;
      int gr = (lane & 15) ^ (4 * (qq & 1) + srow);
      // A (weights): async gll16, swizzle f(R)=R&7 via pre-swizzled source
      gll16(A + (size_t)(m0 + r + srow) * 512 + kt * 128 + gr * 8, &As[r * 128]);
      // Bm (positions): reg-staged fused combine, same layout/swizzle
      int R = r + srow;                     // row in tile (position n0+R)
      int s = lane & 15;                    // slot within 256B row
      size_t goff = (size_t)(n0 + R) * 512 + kt * 128 + gr * 8;
      bf16x8 v0 = *(const bf16x8*)(O0 + goff);
      bf16x8 v1 = *(const bf16x8*)(O1 + goff);
      float iv = invl[R];
      bf16x8 ov;
#pragma unroll
      for (int j = 0; j < 8; ++j)
        ov[j] = (__bf16)(((float)v0[j] + (float)v1[j]) * iv);
      *(bf16x8*)&Bs[R * 128 + s * 8] = ov;
    }
    __syncthreads();
#pragma unroll
    for (int kk = 0; kk < 4; ++kk) {
      bf16x8 af[4], bf[4];
#pragma unroll
      for (int t = 0; t < 4; ++t) {
        int ra = wm * 64 + t * 16 + li;
        af[t] = *(const bf16x8*)&As[ra * 128 + ((kk * 32 + 8 * g) ^ ((ra & 7) * 8))];
        int rb = wn * 64 + t * 16 + li;
        bf[t] = *(const bf16x8*)&Bs[rb * 128 + ((kk * 32 + 8 * g) ^ ((rb & 7) * 8))];
      }
#pragma unroll
      for (int i = 0; i < 4; ++i)
#pragma unroll
        for (int j = 0; j < 4; ++j) acc[i][j] = mfma16(af[i], bf[j], acc[i][j]);
    }
  }
#pragma unroll
  for (int i = 0; i < 4; ++i) {
#pragma unroll
    for (int j = 0; j < 4; ++j) {
      int r = m0 + wm * 64 + i * 16 + 4 * g;   // output channel o
      int c = n0 + wn * 64 + j * 16 + li;      // flat position b*4096+l
      int bb = c >> 12, l = c & 4095;
#pragma unroll
      for (int e = 0; e < 4; ++e) {
        float v = acc[i][j][e] + bias[r + e];
        size_t oi = ((size_t)bb * 512 + (r + e)) * 4096 + l;
        out[oi] = xres[oi] + selu_f(v);
      }
    }
  }
}

// ---------------------------------------------------------------------------
// Flash attention (r7 core loop verbatim — proven 237us) + coalesced O-write.
// ---------------------------------------------------------------------------
__global__ __launch_bounds__(512, 2) void flash_half(
    const __bf16* __restrict__ Q, const __bf16* __restrict__ K,
    const __bf16* __restrict__ VT, __bf16* __restrict__ Op,
    float* __restrict__ stats) {
  __shared__ __align__(16) __bf16 Ks[64][512];    // 64 KB
  __shared__ __align__(16) __bf16 VTs[512][64];   // 64 KB
  __shared__ __align__(16) __bf16 Ps[128][64];    // 16 KB

  const int tid = threadIdx.x;
  const int w = tid >> 6, lane = tid & 63, g = lane >> 4, li = lane & 15;
  const int id = blockIdx.x;
  const int grp = id & 7;                 // XCD group
  const int b = grp >> 1, half = grp & 1;
  const int q0 = (id >> 3) * 128;
  const size_t base = (size_t)b * (4096 * 512);
  const int kvbase = half * 2048;         // element offset of this KV half

  // Q fragments in registers (wave w rows 16w + li); q pre-scaled by QSCALE
  bf16x8 qf[16];
  {
    const __bf16* qp = Q + base + (size_t)(q0 + 16 * w + li) * 512 + 8 * g;
#pragma unroll
    for (int ks = 0; ks < 16; ++ks) qf[ks] = *(const bf16x8*)(qp + ks * 32);
  }

  f32x4 acc[8][4] = {};
  f32x4 lacc = {};
  bf16x8 ones;
#pragma unroll
  for (int j = 0; j < 8; ++j) ones[j] = (__bf16)1.0f;

  auto stageK = [&](int kt) {
#pragma unroll
    for (int i = 0; i < 8; ++i) {
      int r = w * 8 + i;                       // wave-uniform LDS row
      int y = (lane * 16) ^ ((r & 7) << 4);    // pre-swizzled source byte offset
      gll16(K + base + (size_t)(kvbase + kt * 64 + r) * 512 + (y >> 1),
            &Ks[r][0]);
    }
  };
  auto stageVT = [&](int kt) {
    const int drow = lane >> 3;
    const int gr = (lane & 7) ^ drow;
#pragma unroll
    for (int i = 0; i < 8; ++i) {
      int d0 = w * 64 + i * 8;                 // wave-uniform LDS row block
      gll16(VT + (size_t)b * 2097152 + (size_t)(d0 + drow) * 4096 +
                kvbase + kt * 64 + gr * 8,
            &VTs[d0][0]);
    }
  };

  stageK(0);
  stageVT(0);
  __syncthreads();

  for (int kt = 0; kt < 32; ++kt) {
    // ---- S = Q K^T (wave rows 16w.., kv 0..63 of tile), reads Ks ----
    __builtin_amdgcn_s_setprio(1);
    f32x4 s[4] = {};
#pragma unroll
    for (int ks = 0; ks < 16; ++ks) {
      int e = (ks * 32 + 8 * g) ^ ((li & 7) * 8);
#pragma unroll
      for (int kvt = 0; kvt < 4; ++kvt) {
        bf16x8 kf = *(const bf16x8*)&Ks[kvt * 16 + li][e];
        s[kvt] = mfma16(qf[ks], kf, s[kvt]);
      }
    }
    __builtin_amdgcn_s_setprio(0);

    // ---- softmax (no max-shift) + Ps write; s dies here ----
#pragma unroll
    for (int kvt = 0; kvt < 4; ++kvt) {
#pragma unroll
      for (int e = 0; e < 4; ++e) {
        float p = exp2f(s[kvt][e]);
        int row = 16 * w + 4 * g + e;
        int slot = (2 * kvt + (li >> 3)) ^ (row & 7);
        Ps[row][slot * 8 + (li & 7)] = (__bf16)p;
      }
    }
    __syncthreads();  // bar#1: Ps visible; QKT done with Ks; VTs(kt) drained

    if (kt + 1 < 32) stageK(kt + 1);  // overwrite Ks; drains at bar#2

    // ---- PV(kt): bfr from VTs, af from Ps (lean: bfr[4] + one af) ----
#pragma unroll
    for (int ks = 0; ks < 2; ++ks) {
      bf16x8 bfr[4];
#pragma unroll
      for (int ct = 0; ct < 4; ++ct) {
        int dcol = 64 * w + 16 * ct + li;
        int slot = (4 * ks + g) ^ (li & 7);
        bfr[ct] = *(const bf16x8*)&VTs[dcol][slot * 8];
      }
      __builtin_amdgcn_s_setprio(1);
#pragma unroll
      for (int rt = 0; rt < 8; ++rt) {
        int prow = rt * 16 + li;
        int slot = (4 * ks + g) ^ (li & 7);
        bf16x8 af = *(const bf16x8*)&Ps[prow][slot * 8];
        if (rt == w) lacc = mfma16(af, ones, lacc);
#pragma unroll
        for (int ct = 0; ct < 4; ++ct)
          acc[rt][ct] = mfma16(af, bfr[ct], acc[rt][ct]);
      }
      __builtin_amdgcn_s_setprio(0);
    }
    __syncthreads();  // bar#2: PV done with VTs/Ps; stageK drained

    if (kt + 1 < 32) stageVT(kt + 1);  // overwrite VTs; drains at next bar#1
  }

  // ---- write l-sums ----
  if (li == 0)
    *(f32x4*)(stats + half * 16384 + b * 4096 + q0 + 16 * w + 4 * g) = lacc;

  // ---- coalesced O-write: restage each 16-row slice through Ps (dead) ----
  __bf16* C = &Ps[0][0];  // 16 rows x 512 cols bf16 = 16 KB = sizeof(Ps)
  for (int rt = 0; rt < 8; ++rt) {
    __syncthreads();  // previous slice's reads (or final PV) complete
#pragma unroll
    for (int ct = 0; ct < 4; ++ct)
#pragma unroll
      for (int e = 0; e < 4; ++e)
        C[(4 * g + e) * 512 + 64 * w + 16 * ct + li] = (__bf16)acc[rt][ct][e];
    __syncthreads();
#pragma unroll
    for (int rep = 0; rep < 2; ++rep) {
      int ii = rep * 512 + tid;
      int row16 = ii >> 6, col8 = (ii & 63) * 8;
      *(bf16x8*)&Op[(size_t)half * 8388608 + base +
                    (size_t)(q0 + rt * 16 + row16) * 512 + col8] =
          *(const bf16x8*)&C[row16 * 512 + col8];
    }
  }
}

// ---------------------------------------------------------------------------
extern "C" void kernel_launch(void* const* d_in, const int* in_sizes, int n_in,
                              void* d_out, int out_size, void* d_ws, size_t ws_size,
                              hipStream_t stream) {
  const float* x   = (const float*)d_in[0];
  const float* lnw = (const float*)d_in[1];
  const float* lnb = (const float*)d_in[2];
  const float* wq  = (const float*)d_in[3];
  const float* bq  = (const float*)d_in[4];
  const float* wk  = (const float*)d_in[5];
  const float* bk  = (const float*)d_in[6];
  const float* wv  = (const float*)d_in[7];
  const float* bv  = (const float*)d_in[8];
  const float* wp  = (const float*)d_in[9];
  const float* bp  = (const float*)d_in[10];

  char* ws = (char*)d_ws;
  const size_t MB = 1024 * 1024;
  __bf16* h    = (__bf16*)(ws);                 // 16 MB
  __bf16* q    = (__bf16*)(ws + 16 * MB);       // 32 MB (q at +0, k at +8M elems)
  __bf16* vt   = (__bf16*)(ws + 48 * MB);       // 16 MB (V transposed [b][c][l])
  __bf16* wbf  = (__bf16*)(ws + 64 * MB);       // 2 MB (wq|wk|wv|wp bf16)
  __bf16* op   = (__bf16*)(ws + 67 * MB);       // 32 MB (both halves)
  float*  stats= (float*)(ws + 99 * MB);        // 128 KB (l0,l1)

  ln_cvt<<<1536, 256, 0, stream>>>(x, lnw, lnb, h, wq, wk, wv, wp, wbf);
  gemm_qkv<<<1536, 256, 0, stream>>>(h, wbf, bq, bk, bv, q, vt);
  flash_half<<<256, 512, 0, stream>>>(q, q + 8388608, vt, op, stats);
  gemm_pp<<<512, 256, 0, stream>>>(wbf + 3 * 262144, op, op + 8388608, stats,
                                   bp, x, (float*)d_out);
}